// Round 6
// baseline (511.230 us; speedup 1.0000x reference)
//
#include <hip/hip_runtime.h>
#include <hip/hip_bf16.h>

// ---------------------------------------------------------------------------
// EdgeFtLayer fused kernel for MI355X (gfx950).  Round 9.
//
// vs round 8 (487us = 219 fused + 268 aux):
//   * hist: 4 replica counters indexed by blockIdx&3 (same-address atomic
//     serialization /4); scan sums the replicas.
//   * fused: num/den interleaved [dst][c][2] -> each run-flush's two atomics
//     hit ONE 64B line (was two lines 25.6MB apart); out_e stores made
//     nontemporal (128MB write-once; keep L2 for B/num/den); setprio
//     reverted (measured -4us when added in r8).
//   * finalize reads (n0,d0,n1,d1) float4 pairs, writes float2.
// ---------------------------------------------------------------------------

typedef float  f32x4   __attribute__((ext_vector_type(4)));
typedef __bf16 bf16x8  __attribute__((ext_vector_type(8)));
typedef unsigned short ushort8_t __attribute__((ext_vector_type(8)));
typedef unsigned long long u64;

#define EID_MASK  0x7FFFFull   // 19 bits
#define SRC_SHIFT 19
#define DST_SHIFT 35
#define NBIN 50176             // padded N for counters

__device__ __forceinline__ unsigned short f2bf(float f) {
  unsigned int u = __float_as_uint(f);
  return (unsigned short)((u + 0x7FFFu + ((u >> 16) & 1u)) >> 16);
}

__device__ __forceinline__ void store_bf4(unsigned short* p, float4 v) {
  ushort4 u;
  u.x = f2bf(v.x); u.y = f2bf(v.y); u.z = f2bf(v.z); u.w = f2bf(v.w);
  *(ushort4*)p = u;
}

// async 16B global -> LDS (dest = wave-uniform base + lane*16)
__device__ __forceinline__ void async16(void* lds, const void* g) {
  __builtin_amdgcn_global_load_lds(
      (const __attribute__((address_space(1))) unsigned int*)g,
      (__attribute__((address_space(3))) unsigned int*)lds, 16, 0, 0);
}

// ---------------------------------------------------------------------------
// K1 (after memset of cnt_r+chain): hist(x4 replicas) + zero nd + x->bf16 +
// B-pack.  hist blocks first: latency-bound atomics overlap BW-bound stores.
// ---------------------------------------------------------------------------
__global__ void prep_kernel(const int* __restrict__ ei,
                            const float* __restrict__ x,
                            const float* __restrict__ Wa,
                            const float* __restrict__ Wt,
                            const float* __restrict__ We,
                            const float* __restrict__ Wee,
                            int* __restrict__ cnt_r,      // [4][NBIN]
                            float4* __restrict__ zbase,   // nd, N*64 f4
                            unsigned short* __restrict__ xb,
                            unsigned short* __restrict__ Bp,
                            int E, int N) {
  const int tid = threadIdx.x;
  const int H   = (E + 255) >> 8;        // 1954 hist blocks
  const int Z   = (N * 64 + 255) >> 8;   // 12500 zero blocks (nd)
  const int X   = (N * 32 + 255) >> 8;   // 6250 convert blocks
  const int rep = blockIdx.x & 3;
  int b = blockIdx.x;
  if (b < H) {                            // histogram of dst -> replica rep
    int e = b * 256 + tid;
    if (e < E) atomicAdd(&cnt_r[rep * NBIN + ei[E + e]], 1);
    return;
  }
  b -= H;
  if (b < Z) {                            // zero nd (interleaved num/den)
    int i = b * 256 + tid;
    if (i < N * 64) { float4 z = {0.f, 0.f, 0.f, 0.f}; zbase[i] = z; }
    return;
  }
  b -= Z;
  if (b < X) {                            // x -> bf16
    int i = b * 256 + tid;
    if (i < N * 32) {
      float4 v = ((const float4*)x)[i];
      store_bf4(&xb[(size_t)i * 4], v);
    }
    return;
  }
  b -= X;
  {                                       // B pack: 400 blocks, pe in [0,102400)
    int pe = b * 256 + tid;
    int j    = pe & 7;
    int lane = (pe >> 3) & 63;
    int kt   = (pe >> 9) % 10;
    int nt   = pe / 5120;
    int k = kt * 32 + ((lane >> 4) << 3) + j;
    int n = nt * 16 + (lane & 15);
    float v;
    if (n < 128) {
      v = Wa[k * 128 + n];
    } else if (n < 256) {
      v = Wt[k * 128 + (n - 128)];
    } else {
      int c = n - 256;
      if (k < 128)      v = We[k * 64 + c];
      else if (k < 192) v = Wee[(k - 128) * 64 + c];
      else              v = We[(k - 192) * 64 + c];
    }
    Bp[pe] = f2bf(v);
  }
}

// ---------------------------------------------------------------------------
// K2: single-dispatch exclusive scan of (sum of 4 cnt replicas) -> cur
// (decoupled lookback).  NB=196 blocks; chain[b] = block-total+1, 0=unset.
// ---------------------------------------------------------------------------
__global__ void scan_kernel(const int* __restrict__ cnt_r, int* __restrict__ cur,
                            int* __restrict__ chain, int n) {
  __shared__ int ls[256];
  __shared__ int sred[256];
  const int t = threadIdx.x;
  const int b = blockIdx.x;
  const int i = b * 256 + t;
  int v = 0;
  if (i < n)
    v = cnt_r[i] + cnt_r[NBIN + i] + cnt_r[2 * NBIN + i] + cnt_r[3 * NBIN + i];

  // block total via tree reduce; publish IMMEDIATELY
  sred[t] = v;
  __syncthreads();
  for (int off = 128; off > 0; off >>= 1) {
    if (t < off) sred[t] += sred[t + off];
    __syncthreads();
  }
  if (t == 0)
    __hip_atomic_store(&chain[b], sred[0] + 1, __ATOMIC_RELEASE,
                       __HIP_MEMORY_SCOPE_AGENT);

  // local inclusive scan
  ls[t] = v;
  __syncthreads();
  for (int off = 1; off < 256; off <<= 1) {
    int u = (t >= off) ? ls[t - off] : 0;
    __syncthreads();
    ls[t] += u;
    __syncthreads();
  }

  // lookback: lane t polls block t's total (t < b), then block-reduce
  int pv = 0;
  if (t < b) {
    int c;
    do {
      c = __hip_atomic_load(&chain[t], __ATOMIC_ACQUIRE,
                            __HIP_MEMORY_SCOPE_AGENT);
    } while (c == 0);
    pv = c - 1;
  }
  sred[t] = pv;
  __syncthreads();
  for (int off = 128; off > 0; off >>= 1) {
    if (t < off) sred[t] += sred[t + off];
    __syncthreads();
  }
  if (i < n) cur[i] = ls[t] - v + sred[0];   // exclusive + block offset
}

// --------------------------- scatter (max TLP) ------------------------------
__global__ void scatter_kernel(const int* __restrict__ ei, int* __restrict__ cur,
                               u64* __restrict__ pk, int E) {
  int e = blockIdx.x * 256 + threadIdx.x;
  if (e < E) {
    int s = ei[e];
    int d = ei[E + e];
    int pos = atomicAdd(&cur[d], 1);
    pk[pos] = (u64)(unsigned)e | ((u64)(unsigned)s << SRC_SHIFT) |
              ((u64)(unsigned)d << DST_SHIFT);
  }
}

// ---------------------------------------------------------------------------
// K4: fused gather + GEMM + register exact-run segmented-reduction epilogue.
// 64 sorted edges / block, 4 waves; wave w owns n-tiles {w, w+4, w+8, w+12, w+16}.
// nd layout: [dst][c][2] -> num at dst*256+2c, den at dst*256+2c+1 (same line).
// ---------------------------------------------------------------------------
__global__ __launch_bounds__(256, 3) void fused_edge_kernel(
    const unsigned short* __restrict__ xb,   // bf16 x, [N,128]
    const float* __restrict__ ea,            // f32 edge_attr, [E,64]
    const u64*   __restrict__ pk,            // packed {eid,src,dst} sorted by dst
    const unsigned short* __restrict__ Bp,
    float* __restrict__ nd,
    float* __restrict__ out_e,
    const float* __restrict__ a_prelu,
    int E) {
  // 48KB A-region (DMA dest, dense + source-swizzled)
  __shared__ __align__(16) char smem[64 * 128 * 2 * 2 + 64 * 64 * 4];  // 49152
  unsigned short* At_dst = (unsigned short*)smem;              // 64x128 bf16
  unsigned short* At_src = (unsigned short*)(smem + 16384);    // 64x128 bf16
  float*          Aea    = (float*)(smem + 32768);             // 64x64  f32
  __shared__ int s_dst[64];
  __shared__ int s_eid[64];

  const int tid = threadIdx.x;
  const int eb  = blockIdx.x * 64;
  const int nvalid = min(64, E - eb);

  const int w  = tid >> 6;
  const int l  = tid & 63;
  const int g4 = l >> 4;          // 16-lane quarter
  const int j  = l & 15;          // dest 16B chunk within row

  // header for epilogue (runs concurrent with DMA issue below)
  if (tid < 64) {
    u64 p = pk[min(eb + tid, E - 1)];
    s_eid[tid] = (int)(p & EID_MASK);
    s_dst[tid] = (int)((p >> DST_SHIFT) & 0xFFFF);
  }

  // ---- async gather: per-lane global addrs (clamped), no pre-barrier ------
  // instr t covers rows [w*16 + t*4, +4); lane writes LDS base + l*16.
  // LDS slot jj of row r holds global 16B-chunk (jj ^ (r&7)).
  #pragma unroll
  for (int t = 0; t < 4; ++t) {
    int row = w * 16 + t * 4 + g4;
    u64 p   = pk[min(eb + row, E - 1)];
    int ee  = (int)(p & EID_MASK);
    int ns  = (int)((p >> SRC_SHIFT) & 0xFFFF);
    int nd_ = (int)((p >> DST_SHIFT) & 0xFFFF);
    int cD  = j ^ (row & 7);             // swizzled global chunk
    async16(&At_dst[(w * 16 + t * 4) * 128], xb + (size_t)nd_ * 128 + cD * 8);
    async16(&At_src[(w * 16 + t * 4) * 128], xb + (size_t)ns * 128 + cD * 8);
    async16(&Aea   [(w * 16 + t * 4) * 64 ], ea + (size_t)ee * 64  + cD * 4);
  }

  const ushort8_t* BpV = (const ushort8_t*)Bp;  // frag idx = (nt*10+kc)*64 + l

  // B double-buffer: preload kc=0 BEFORE the barrier (hidden under DMA wait)
  bf16x8 bv[2][5];
  #pragma unroll
  for (int i = 0; i < 5; ++i)
    bv[0][i] = __builtin_bit_cast(bf16x8, BpV[((w + 4 * i) * 10 + 0) * 64 + l]);

  const float slope = a_prelu[0];   // scalar load hidden under DMA wait

  __syncthreads();   // drains vmcnt(0): DMA + header complete

  const int lrow = l & 15;

  f32x4 acc[4][5];
  #pragma unroll
  for (int mt = 0; mt < 4; ++mt)
    #pragma unroll
    for (int i = 0; i < 5; ++i)
      acc[mt][i] = (f32x4){0.f, 0.f, 0.f, 0.f};

  #pragma unroll
  for (int kc = 0; kc < 10; ++kc) {
    const int cur_ = kc & 1;
    const int nxt_ = cur_ ^ 1;
    // prefetch kc+1 B frags (5 global loads in flight under the 20 MFMAs)
    if (kc < 9) {
      #pragma unroll
      for (int i = 0; i < 5; ++i)
        bv[nxt_][i] = __builtin_bit_cast(
            bf16x8, BpV[((w + 4 * i) * 10 + (kc + 1)) * 64 + l]);
    }
    // A fragments for this kc
    bf16x8 av[4];
    #pragma unroll
    for (int mt = 0; mt < 4; ++mt) {
      int row = mt * 16 + lrow;
      int sw  = row & 7;
      if (kc < 4) {                      // x[dst], k-cols [0,128)
        int c = kc * 4 + g4;
        av[mt] = __builtin_bit_cast(
            bf16x8, *(const ushort8_t*)&At_dst[row * 128 + ((c ^ sw) << 3)]);
      } else if (kc < 6) {               // edge_attr, k-cols [128,192)
        int c0 = (kc - 4) * 8 + (g4 << 1);
        float4 f0 = *(const float4*)&Aea[row * 64 + (((c0    ) ^ sw) << 2)];
        float4 f1 = *(const float4*)&Aea[row * 64 + (((c0 + 1) ^ sw) << 2)];
        bf16x8 t;
        t[0] = (__bf16)f0.x; t[1] = (__bf16)f0.y;
        t[2] = (__bf16)f0.z; t[3] = (__bf16)f0.w;
        t[4] = (__bf16)f1.x; t[5] = (__bf16)f1.y;
        t[6] = (__bf16)f1.z; t[7] = (__bf16)f1.w;
        av[mt] = t;
      } else {                           // x[src], k-cols [192,320)
        int c = (kc - 6) * 4 + g4;
        av[mt] = __builtin_bit_cast(
            bf16x8, *(const ushort8_t*)&At_src[row * 128 + ((c ^ sw) << 3)]);
      }
    }
    #pragma unroll
    for (int mt = 0; mt < 4; ++mt)
      #pragma unroll
      for (int i = 0; i < 5; ++i)
        acc[mt][i] = __builtin_amdgcn_mfma_f32_16x16x32_bf16(
            av[mt], bv[cur_][i], acc[mt][i], 0, 0, 0);
  }

  // ------------------- epilogue (ZERO barriers) -------------------
  // C layout: row = (lane>>4)*4 + reg, col = lane&15
  const int rbase = g4 << 2;
  const int ccol  = l & 15;

  // new_e_feat stores (nontemporal: write-once stream, keep L2 for B/nd)
  #pragma unroll
  for (int mt = 0; mt < 4; ++mt) {
    const int m0 = mt * 16 + rbase;
    #pragma unroll
    for (int r = 0; r < 4; ++r) {
      int m = m0 + r;
      if (m < nvalid)
        __builtin_nontemporal_store(
            acc[mt][4][r], &out_e[(size_t)s_eid[m] * 64 + w * 16 + ccol]);
    }
  }

  // ---- wave-uniform run-end mask: bit k set iff row k ends its dst-run ----
  {
    int dme = s_dst[l];
    int dnx = (l < 63) ? s_dst[l + 1] : dme;
    bool isend = (l >= nvalid - 1) || (dnx != dme);
    unsigned long long endm = __ballot(isend);

    // ---- register exact-run segmented reduce (num & den together) ----
    #pragma unroll
    for (int i2 = 0; i2 < 2; ++i2) {
      const int c2 = ((w + 4 * i2) * 16 + ccol) << 1;   // interleaved col*2
      float ptn = 0.f, ptd = 0.f;         // prev m-tile tail (valid in g4==3)
      #pragma unroll
      for (int mt = 0; mt < 4; ++mt) {
        const int A = mt * 16 + rbase;    // abs start row of lane's chunk
        // per-row contributions (zeroed past nvalid)
        float vn[4], vd[4];
        #pragma unroll
        for (int r = 0; r < 4; ++r) {
          float lg = acc[mt][i2][r];
          float e_ = __expf(lg >= 0.f ? lg : slope * lg);
          bool ok = (A + r) < nvalid;
          vd[r] = ok ? e_ : 0.f;
          vn[r] = ok ? e_ * acc[mt][i2 + 2][r] : 0.f;
        }
        // local pass: flush complete interior runs, keep first-seg + tail
        float tn = 0.f, td = 0.f, fn = 0.f, fd = 0.f;
        int firstrow = -1;
        #pragma unroll
        for (int r = 0; r < 4; ++r) {
          tn += vn[r]; td += vd[r];
          if ((endm >> (A + r)) & 1ull) {
            if (firstrow < 0) {
              fn = tn; fd = td; firstrow = A + r;
            } else {
              size_t base = (size_t)s_dst[A + r] * 256 + c2;
              unsafeAtomicAdd(&nd[base], tn);
              unsafeAtomicAdd(&nd[base + 1], td);
            }
            tn = 0.f; td = 0.f;
          }
        }
        const bool seen = (firstrow >= 0);
        // carry chain across quarters (and from previous m-tile into g4==0)
        const bool cont_tile =
            (mt > 0) && !((endm >> (mt * 16 - 1)) & 1ull);  // wave-uniform
        float cin_n = __shfl(ptn, (l & 15) + 48);
        float cin_d = __shfl(ptd, (l & 15) + 48);
        int shp = (A == 0) ? 0 : (A - 1);                   // safe shift
        bool open_in = (g4 == 0) ? cont_tile
                                 : !((endm >> shp) & 1ull);
        float cn = (g4 == 0 && cont_tile) ? cin_n : 0.f;
        float cd = (g4 == 0 && cont_tile) ? cin_d : 0.f;
        #pragma unroll
        for (int s = 0; s < 3; ++s) {
          float on = seen ? tn : (tn + cn);
          float od = seen ? td : (td + cd);
          float un = __shfl_up(on, 16);
          float ud = __shfl_up(od, 16);
          if (g4 == s + 1) {
            cn = open_in ? un : 0.f;
            cd = open_in ? ud : 0.f;
          }
        }
        // flush first segment with its incoming carry
        if (seen) {
          size_t base = (size_t)s_dst[firstrow] * 256 + c2;
          unsafeAtomicAdd(&nd[base], fn + cn);
          unsafeAtomicAdd(&nd[base + 1], fd + cd);
        }
        // tile tail out (consumed from g4==3 lanes next iteration)
        ptn = seen ? tn : (tn + cn);
        ptd = seen ? td : (td + cd);
      }
    }
  }
}

// ---------------------------------------------------------------------------
// K5: finalize.  nd float4 = (n0,d0,n1,d1) -> out float2.  i over N*64.
// ---------------------------------------------------------------------------
__global__ void finalize_kernel(const float4* __restrict__ nd4,
                                const float* __restrict__ bT,
                                float2* __restrict__ out2, int total4) {
  int i = blockIdx.x * 256 + threadIdx.x;
  if (i < total4) {
    float4 v = nd4[i];
    int p = (i & 63) << 1;              // column pair
    float2 o;
    o.x = v.x / (v.y + 1e-16f) + bT[p];
    o.y = v.z / (v.w + 1e-16f) + bT[p + 1];
    out2[i] = o;
  }
}

extern "C" void kernel_launch(void* const* d_in, const int* in_sizes, int n_in,
                              void* d_out, int out_size, void* d_ws, size_t ws_size,
                              hipStream_t stream) {
  const float* x   = (const float*)d_in[0];
  const int*   ei  = (const int*)d_in[1];
  const float* ea  = (const float*)d_in[2];
  const float* Wa  = (const float*)d_in[3];
  const float* Wt  = (const float*)d_in[4];
  const float* bT  = (const float*)d_in[5];
  const float* We  = (const float*)d_in[6];
  const float* Wee = (const float*)d_in[7];
  const float* ap  = (const float*)d_in[8];

  const int N = in_sizes[0] / 128;          // 50000
  const int E = in_sizes[1] / 2;            // 500000
  const int NB = (N + 255) / 256;           // 196

  // workspace layout (byte offsets)
  char* ws = (char*)d_ws;
  unsigned short* Bp = (unsigned short*)ws;                       // 204,800
  float* nd  = (float*)(ws + 204800);                             // 51.2 MB
  int* cnt_r = (int*)(ws + 204800 + (size_t)N * 256 * 4);         // 4*NBIN ints
  int* chain = cnt_r + 4 * NBIN;                                  // 1 KB
  int* cur   = chain + 256;                                       // 200,704
  u64* pk    = (u64*)(cur + NBIN);                                // 4 MB
  unsigned short* x_bf16 = (unsigned short*)(pk + 500224);        // 12.8 MB

  float* out_x = (float*)d_out;
  float* out_e = out_x + (size_t)N * 128;

  // zero cnt replicas + chain (contiguous; nd zeroed inside prep grid)
  hipMemsetAsync(cnt_r, 0, (4 * NBIN + 256) * sizeof(int), stream);

  // K1: hist(x4) + zero nd + x->bf16 + B-pack
  {
    int H = (E + 255) >> 8;
    int Z = (N * 64 + 255) >> 8;
    int X = (N * 32 + 255) >> 8;
    prep_kernel<<<H + Z + X + 400, 256, 0, stream>>>(
        ei, x, Wa, Wt, We, Wee, cnt_r, (float4*)nd, x_bf16, Bp, E, N);
  }

  // K2: single-dispatch decoupled-lookback exclusive scan (sums replicas)
  scan_kernel<<<NB, 256, 0, stream>>>(cnt_r, cur, chain, N);

  // K3: scatter at full TLP (packed 8B payload)
  scatter_kernel<<<(E + 255) / 256, 256, 0, stream>>>(ei, cur, pk, E);

  // K4: fused gather + GEMM + register segmented reduce
  fused_edge_kernel<<<(E + 63) / 64, 256, 0, stream>>>(
      x_bf16, ea, pk, Bp, nd, out_e, ap, E);

  // K5: finalize
  finalize_kernel<<<(N * 64 + 255) / 256, 256, 0, stream>>>(
      (const float4*)nd, bT, (float2*)d_out, N * 64);
}

// Round 7
// 466.301 us; speedup vs baseline: 1.0964x; 1.0964x over previous
//
#include <hip/hip_runtime.h>
#include <hip/hip_bf16.h>

// ---------------------------------------------------------------------------
// EdgeFtLayer fused kernel for MI355X (gfx950).  Round 10.
//
// vs round 9 (511us = 240 fused + 271 aux, regression):
//   * Fused REVERTED to round-7 proven config (215us): separate num/den
//     arrays, plain out_e stores (NT stores cost +98MB HBM writes: scattered
//     4B stores need L2 write-combining), no setprio.  u64 pk kept.
//   * hist now captures each edge's within-dst rank for free:
//       rank[e] = atomicAdd(&cnt[d], 1)   (return was unused before)
//     -> scatter becomes ATOMIC-FREE: pos = cur[d] + rank[e].  This deletes
//     one entire 500K-random-atomic pass from the aux chain (r9 showed the
//     aux bottleneck is atomic throughput, not same-address conflicts:
//     4x replication moved nothing -> replicas dropped).
//   * num/den/cnt/chain zeroed by one SDMA memset (r6's cheapest variant).
// ---------------------------------------------------------------------------

typedef float  f32x4   __attribute__((ext_vector_type(4)));
typedef __bf16 bf16x8  __attribute__((ext_vector_type(8)));
typedef unsigned short ushort8_t __attribute__((ext_vector_type(8)));
typedef unsigned long long u64;

#define EID_MASK  0x7FFFFull   // 19 bits
#define SRC_SHIFT 19
#define DST_SHIFT 35
#define NBIN 50176             // padded N for counters

__device__ __forceinline__ unsigned short f2bf(float f) {
  unsigned int u = __float_as_uint(f);
  return (unsigned short)((u + 0x7FFFu + ((u >> 16) & 1u)) >> 16);
}

__device__ __forceinline__ void store_bf4(unsigned short* p, float4 v) {
  ushort4 u;
  u.x = f2bf(v.x); u.y = f2bf(v.y); u.z = f2bf(v.z); u.w = f2bf(v.w);
  *(ushort4*)p = u;
}

// async 16B global -> LDS (dest = wave-uniform base + lane*16)
__device__ __forceinline__ void async16(void* lds, const void* g) {
  __builtin_amdgcn_global_load_lds(
      (const __attribute__((address_space(1))) unsigned int*)g,
      (__attribute__((address_space(3))) unsigned int*)lds, 16, 0, 0);
}

// ---------------------------------------------------------------------------
// K1 (after memset of num/den/cnt/chain): hist(+rank) + x->bf16 + B-pack.
// hist blocks first: latency-bound atomics overlap the BW-bound stores.
// ---------------------------------------------------------------------------
__global__ void prep_kernel(const int* __restrict__ ei,
                            const float* __restrict__ x,
                            const float* __restrict__ Wa,
                            const float* __restrict__ Wt,
                            const float* __restrict__ We,
                            const float* __restrict__ Wee,
                            int* __restrict__ cnt,
                            int* __restrict__ rank,
                            unsigned short* __restrict__ xb,
                            unsigned short* __restrict__ Bp,
                            int E, int N) {
  const int tid = threadIdx.x;
  const int H   = (E + 255) >> 8;        // 1954 hist blocks
  const int X   = (N * 32 + 255) >> 8;   // 6250 convert blocks
  int b = blockIdx.x;
  if (b < H) {                            // histogram of dst + rank capture
    int e = b * 256 + tid;
    if (e < E) rank[e] = atomicAdd(&cnt[ei[E + e]], 1);
    return;
  }
  b -= H;
  if (b < X) {                            // x -> bf16
    int i = b * 256 + tid;
    if (i < N * 32) {
      float4 v = ((const float4*)x)[i];
      store_bf4(&xb[(size_t)i * 4], v);
    }
    return;
  }
  b -= X;
  {                                       // B pack: 400 blocks, pe in [0,102400)
    int pe = b * 256 + tid;
    int j    = pe & 7;
    int lane = (pe >> 3) & 63;
    int kt   = (pe >> 9) % 10;
    int nt   = pe / 5120;
    int k = kt * 32 + ((lane >> 4) << 3) + j;
    int n = nt * 16 + (lane & 15);
    float v;
    if (n < 128) {
      v = Wa[k * 128 + n];
    } else if (n < 256) {
      v = Wt[k * 128 + (n - 128)];
    } else {
      int c = n - 256;
      if (k < 128)      v = We[k * 64 + c];
      else if (k < 192) v = Wee[(k - 128) * 64 + c];
      else              v = We[(k - 192) * 64 + c];
    }
    Bp[pe] = f2bf(v);
  }
}

// ---------------------------------------------------------------------------
// K2: single-dispatch exclusive scan of cnt -> cur (decoupled lookback).
// NB=196 blocks; chain[b] = block-total+1, 0 = unset (memset'd).
// ---------------------------------------------------------------------------
__global__ void scan_kernel(const int* __restrict__ cnt, int* __restrict__ cur,
                            int* __restrict__ chain, int n) {
  __shared__ int ls[256];
  __shared__ int sred[256];
  const int t = threadIdx.x;
  const int b = blockIdx.x;
  const int i = b * 256 + t;
  int v = (i < n) ? cnt[i] : 0;

  // block total via tree reduce; publish IMMEDIATELY
  sred[t] = v;
  __syncthreads();
  for (int off = 128; off > 0; off >>= 1) {
    if (t < off) sred[t] += sred[t + off];
    __syncthreads();
  }
  if (t == 0)
    __hip_atomic_store(&chain[b], sred[0] + 1, __ATOMIC_RELEASE,
                       __HIP_MEMORY_SCOPE_AGENT);

  // local inclusive scan
  ls[t] = v;
  __syncthreads();
  for (int off = 1; off < 256; off <<= 1) {
    int u = (t >= off) ? ls[t - off] : 0;
    __syncthreads();
    ls[t] += u;
    __syncthreads();
  }

  // lookback: lane t polls block t's total (t < b), then block-reduce
  int pv = 0;
  if (t < b) {
    int c;
    do {
      c = __hip_atomic_load(&chain[t], __ATOMIC_ACQUIRE,
                            __HIP_MEMORY_SCOPE_AGENT);
    } while (c == 0);
    pv = c - 1;
  }
  sred[t] = pv;
  __syncthreads();
  for (int off = 128; off > 0; off >>= 1) {
    if (t < off) sred[t] += sred[t + off];
    __syncthreads();
  }
  if (i < n) cur[i] = ls[t] - v + sred[0];   // exclusive + block offset
}

// --------------------------- scatter (ATOMIC-FREE) --------------------------
__global__ void scatter_kernel(const int* __restrict__ ei,
                               const int* __restrict__ cur,
                               const int* __restrict__ rank,
                               u64* __restrict__ pk, int E) {
  int e = blockIdx.x * 256 + threadIdx.x;
  if (e < E) {
    int s = ei[e];
    int d = ei[E + e];
    int pos = cur[d] + rank[e];
    pk[pos] = (u64)(unsigned)e | ((u64)(unsigned)s << SRC_SHIFT) |
              ((u64)(unsigned)d << DST_SHIFT);
  }
}

// ---------------------------------------------------------------------------
// K4: fused gather + GEMM + register exact-run segmented-reduction epilogue.
// 64 sorted edges / block, 4 waves; wave w owns n-tiles {w, w+4, w+8, w+12, w+16}.
// ---------------------------------------------------------------------------
__global__ __launch_bounds__(256, 3) void fused_edge_kernel(
    const unsigned short* __restrict__ xb,   // bf16 x, [N,128]
    const float* __restrict__ ea,            // f32 edge_attr, [E,64]
    const u64*   __restrict__ pk,            // packed {eid,src,dst} sorted by dst
    const unsigned short* __restrict__ Bp,
    float* __restrict__ num,
    float* __restrict__ den,
    float* __restrict__ out_e,
    const float* __restrict__ a_prelu,
    int E) {
  // 48KB A-region (DMA dest, dense + source-swizzled)
  __shared__ __align__(16) char smem[64 * 128 * 2 * 2 + 64 * 64 * 4];  // 49152
  unsigned short* At_dst = (unsigned short*)smem;              // 64x128 bf16
  unsigned short* At_src = (unsigned short*)(smem + 16384);    // 64x128 bf16
  float*          Aea    = (float*)(smem + 32768);             // 64x64  f32
  __shared__ int s_dst[64];
  __shared__ int s_eid[64];

  const int tid = threadIdx.x;
  const int eb  = blockIdx.x * 64;
  const int nvalid = min(64, E - eb);

  const int w  = tid >> 6;
  const int l  = tid & 63;
  const int g4 = l >> 4;          // 16-lane quarter
  const int j  = l & 15;          // dest 16B chunk within row

  // header for epilogue (runs concurrent with DMA issue below)
  if (tid < 64) {
    u64 p = pk[min(eb + tid, E - 1)];
    s_eid[tid] = (int)(p & EID_MASK);
    s_dst[tid] = (int)((p >> DST_SHIFT) & 0xFFFF);
  }

  // ---- async gather: per-lane global addrs (clamped), no pre-barrier ------
  // instr t covers rows [w*16 + t*4, +4); lane writes LDS base + l*16.
  // LDS slot jj of row r holds global 16B-chunk (jj ^ (r&7)).
  #pragma unroll
  for (int t = 0; t < 4; ++t) {
    int row = w * 16 + t * 4 + g4;
    u64 p   = pk[min(eb + row, E - 1)];
    int ee  = (int)(p & EID_MASK);
    int ns  = (int)((p >> SRC_SHIFT) & 0xFFFF);
    int nd  = (int)((p >> DST_SHIFT) & 0xFFFF);
    int cD  = j ^ (row & 7);             // swizzled global chunk
    async16(&At_dst[(w * 16 + t * 4) * 128], xb + (size_t)nd * 128 + cD * 8);
    async16(&At_src[(w * 16 + t * 4) * 128], xb + (size_t)ns * 128 + cD * 8);
    async16(&Aea   [(w * 16 + t * 4) * 64 ], ea + (size_t)ee * 64  + cD * 4);
  }

  const ushort8_t* BpV = (const ushort8_t*)Bp;  // frag idx = (nt*10+kc)*64 + l

  // B double-buffer: preload kc=0 BEFORE the barrier (hidden under DMA wait)
  bf16x8 bv[2][5];
  #pragma unroll
  for (int i = 0; i < 5; ++i)
    bv[0][i] = __builtin_bit_cast(bf16x8, BpV[((w + 4 * i) * 10 + 0) * 64 + l]);

  const float slope = a_prelu[0];   // scalar load hidden under DMA wait

  __syncthreads();   // drains vmcnt(0): DMA + header complete

  const int lrow = l & 15;

  f32x4 acc[4][5];
  #pragma unroll
  for (int mt = 0; mt < 4; ++mt)
    #pragma unroll
    for (int i = 0; i < 5; ++i)
      acc[mt][i] = (f32x4){0.f, 0.f, 0.f, 0.f};

  #pragma unroll
  for (int kc = 0; kc < 10; ++kc) {
    const int cur_ = kc & 1;
    const int nxt_ = cur_ ^ 1;
    // prefetch kc+1 B frags (5 global loads in flight under the 20 MFMAs)
    if (kc < 9) {
      #pragma unroll
      for (int i = 0; i < 5; ++i)
        bv[nxt_][i] = __builtin_bit_cast(
            bf16x8, BpV[((w + 4 * i) * 10 + (kc + 1)) * 64 + l]);
    }
    // A fragments for this kc
    bf16x8 av[4];
    #pragma unroll
    for (int mt = 0; mt < 4; ++mt) {
      int row = mt * 16 + lrow;
      int sw  = row & 7;
      if (kc < 4) {                      // x[dst], k-cols [0,128)
        int c = kc * 4 + g4;
        av[mt] = __builtin_bit_cast(
            bf16x8, *(const ushort8_t*)&At_dst[row * 128 + ((c ^ sw) << 3)]);
      } else if (kc < 6) {               // edge_attr, k-cols [128,192)
        int c0 = (kc - 4) * 8 + (g4 << 1);
        float4 f0 = *(const float4*)&Aea[row * 64 + (((c0    ) ^ sw) << 2)];
        float4 f1 = *(const float4*)&Aea[row * 64 + (((c0 + 1) ^ sw) << 2)];
        bf16x8 t;
        t[0] = (__bf16)f0.x; t[1] = (__bf16)f0.y;
        t[2] = (__bf16)f0.z; t[3] = (__bf16)f0.w;
        t[4] = (__bf16)f1.x; t[5] = (__bf16)f1.y;
        t[6] = (__bf16)f1.z; t[7] = (__bf16)f1.w;
        av[mt] = t;
      } else {                           // x[src], k-cols [192,320)
        int c = (kc - 6) * 4 + g4;
        av[mt] = __builtin_bit_cast(
            bf16x8, *(const ushort8_t*)&At_src[row * 128 + ((c ^ sw) << 3)]);
      }
    }
    #pragma unroll
    for (int mt = 0; mt < 4; ++mt)
      #pragma unroll
      for (int i = 0; i < 5; ++i)
        acc[mt][i] = __builtin_amdgcn_mfma_f32_16x16x32_bf16(
            av[mt], bv[cur_][i], acc[mt][i], 0, 0, 0);
  }

  // ------------------- epilogue (ZERO barriers) -------------------
  // C layout: row = (lane>>4)*4 + reg, col = lane&15
  const int rbase = g4 << 2;
  const int ccol  = l & 15;

  // new_e_feat stores (plain: L2 write-combines the scattered 4B stores)
  #pragma unroll
  for (int mt = 0; mt < 4; ++mt) {
    const int m0 = mt * 16 + rbase;
    #pragma unroll
    for (int r = 0; r < 4; ++r) {
      int m = m0 + r;
      if (m < nvalid)
        out_e[(size_t)s_eid[m] * 64 + w * 16 + ccol] = acc[mt][4][r];
    }
  }

  // ---- wave-uniform run-end mask: bit k set iff row k ends its dst-run ----
  {
    int dme = s_dst[l];
    int dnx = (l < 63) ? s_dst[l + 1] : dme;
    bool isend = (l >= nvalid - 1) || (dnx != dme);
    unsigned long long endm = __ballot(isend);

    // ---- register exact-run segmented reduce (num & den together) ----
    #pragma unroll
    for (int i2 = 0; i2 < 2; ++i2) {
      const int c = (w + 4 * i2) * 16 + ccol;
      float ptn = 0.f, ptd = 0.f;         // prev m-tile tail (valid in g4==3)
      #pragma unroll
      for (int mt = 0; mt < 4; ++mt) {
        const int A = mt * 16 + rbase;    // abs start row of lane's chunk
        // per-row contributions (zeroed past nvalid)
        float vn[4], vd[4];
        #pragma unroll
        for (int r = 0; r < 4; ++r) {
          float lg = acc[mt][i2][r];
          float e_ = __expf(lg >= 0.f ? lg : slope * lg);
          bool ok = (A + r) < nvalid;
          vd[r] = ok ? e_ : 0.f;
          vn[r] = ok ? e_ * acc[mt][i2 + 2][r] : 0.f;
        }
        // local pass: flush complete interior runs, keep first-seg + tail
        float tn = 0.f, td = 0.f, fn = 0.f, fd = 0.f;
        int firstrow = -1;
        #pragma unroll
        for (int r = 0; r < 4; ++r) {
          tn += vn[r]; td += vd[r];
          if ((endm >> (A + r)) & 1ull) {
            if (firstrow < 0) {
              fn = tn; fd = td; firstrow = A + r;
            } else {
              int dd = s_dst[A + r];
              unsafeAtomicAdd(&num[(size_t)dd * 128 + c], tn);
              unsafeAtomicAdd(&den[(size_t)dd * 128 + c], td);
            }
            tn = 0.f; td = 0.f;
          }
        }
        const bool seen = (firstrow >= 0);
        // carry chain across quarters (and from previous m-tile into g4==0)
        const bool cont_tile =
            (mt > 0) && !((endm >> (mt * 16 - 1)) & 1ull);  // wave-uniform
        float cin_n = __shfl(ptn, (l & 15) + 48);
        float cin_d = __shfl(ptd, (l & 15) + 48);
        int shp = (A == 0) ? 0 : (A - 1);                   // safe shift
        bool open_in = (g4 == 0) ? cont_tile
                                 : !((endm >> shp) & 1ull);
        float cn = (g4 == 0 && cont_tile) ? cin_n : 0.f;
        float cd = (g4 == 0 && cont_tile) ? cin_d : 0.f;
        #pragma unroll
        for (int s = 0; s < 3; ++s) {
          float on = seen ? tn : (tn + cn);
          float od = seen ? td : (td + cd);
          float un = __shfl_up(on, 16);
          float ud = __shfl_up(od, 16);
          if (g4 == s + 1) {
            cn = open_in ? un : 0.f;
            cd = open_in ? ud : 0.f;
          }
        }
        // flush first segment with its incoming carry
        if (seen) {
          int dd = s_dst[firstrow];
          unsafeAtomicAdd(&num[(size_t)dd * 128 + c], fn + cn);
          unsafeAtomicAdd(&den[(size_t)dd * 128 + c], fd + cd);
        }
        // tile tail out (consumed from g4==3 lanes next iteration)
        ptn = seen ? tn : (tn + cn);
        ptd = seen ? td : (td + cd);
      }
    }
  }
}

// ---------------------------------------------------------------------------
// K5: finalize (vectorized)
// ---------------------------------------------------------------------------
__global__ void finalize_kernel(const float4* __restrict__ num4,
                                const float4* __restrict__ den4,
                                const float4* __restrict__ bT4,
                                float4* __restrict__ out4, int total4) {
  int i = blockIdx.x * 256 + threadIdx.x;
  if (i < total4) {
    float4 n = num4[i];
    float4 d = den4[i];
    float4 b = bT4[i & 31];
    float4 o;
    o.x = n.x / (d.x + 1e-16f) + b.x;
    o.y = n.y / (d.y + 1e-16f) + b.y;
    o.z = n.z / (d.z + 1e-16f) + b.z;
    o.w = n.w / (d.w + 1e-16f) + b.w;
    out4[i] = o;
  }
}

extern "C" void kernel_launch(void* const* d_in, const int* in_sizes, int n_in,
                              void* d_out, int out_size, void* d_ws, size_t ws_size,
                              hipStream_t stream) {
  const float* x   = (const float*)d_in[0];
  const int*   ei  = (const int*)d_in[1];
  const float* ea  = (const float*)d_in[2];
  const float* Wa  = (const float*)d_in[3];
  const float* Wt  = (const float*)d_in[4];
  const float* bT  = (const float*)d_in[5];
  const float* We  = (const float*)d_in[6];
  const float* Wee = (const float*)d_in[7];
  const float* ap  = (const float*)d_in[8];

  const int N = in_sizes[0] / 128;          // 50000
  const int E = in_sizes[1] / 2;            // 500000
  const int NB = (N + 255) / 256;           // 196

  // workspace layout
  char* ws = (char*)d_ws;
  unsigned short* Bp = (unsigned short*)ws;                       // 204,800
  float* num = (float*)(ws + 204800);                             // 25.6 MB
  float* den = num + (size_t)N * 128;                             // 25.6 MB
  int* cnt   = (int*)(ws + 204800 + (size_t)N * 128 * 8);         // NBIN ints
  int* chain = cnt + NBIN;                                        // 1 KB
  int* cur   = chain + 256;                                       // NBIN ints
  int* rank  = cur + NBIN;                                        // 2 MB
  u64* pk    = (u64*)(rank + 500224);                             // 4 MB
  unsigned short* x_bf16 = (unsigned short*)(pk + 500224);        // 12.8 MB

  float* out_x = (float*)d_out;
  float* out_e = out_x + (size_t)N * 128;

  // zero num+den+cnt+chain in ONE SDMA memset (contiguous)
  hipMemsetAsync(num, 0,
                 (size_t)N * 128 * 8 + (NBIN + 256) * sizeof(int), stream);

  // K1: hist(+rank) + x->bf16 + B-pack
  {
    int H = (E + 255) >> 8;
    int X = (N * 32 + 255) >> 8;
    prep_kernel<<<H + X + 400, 256, 0, stream>>>(
        ei, x, Wa, Wt, We, Wee, cnt, rank, x_bf16, Bp, E, N);
  }

  // K2: single-dispatch decoupled-lookback exclusive scan
  scan_kernel<<<NB, 256, 0, stream>>>(cnt, cur, chain, N);

  // K3: scatter, atomic-free
  scatter_kernel<<<(E + 255) / 256, 256, 0, stream>>>(ei, cur, rank, pk, E);

  // K4: fused gather + GEMM + register segmented reduce
  fused_edge_kernel<<<(E + 63) / 64, 256, 0, stream>>>(
      x_bf16, ea, pk, Bp, num, den, out_e, ap, E);

  // K5: finalize
  finalize_kernel<<<(N * 32 + 255) / 256, 256, 0, stream>>>(
      (const float4*)num, (const float4*)den, (const float4*)bT,
      (float4*)d_out, N * 32);
}